// Round 4
// baseline (1029.913 us; speedup 1.0000x reference)
//
#include <hip/hip_runtime.h>

#define MAX_ITEMS 100000
constexpr int B = 4096;
constexpr int D = 512;
constexpr long long ACT_ELEMS  = (long long)B * D;               // 2097152
constexpr long long HIST_ELEMS = (long long)(MAX_ITEMS + 1) * D; // 51200512
constexpr long long NG  = (HIST_ELEMS - 3) / 4;  // 12800127 dst-aligned float4 groups
constexpr long long NG4 = HIST_ELEMS / 4;        // 12800128 src float4 groups (exact)
// d_out layout: [0, ACT) activations, [ACT] loss, [ACT+1, ACT+1+HIST) new_history.
// outh = out + ACT+1 (4B-aligned); outh+3 is 16B-aligned.

// ---------------------------------------------------------------------------
// p1: pure-READ probe. 6 passes alternating hist / probeBuf (205 MB each, so
// the working set (410 MB) exceeds the 256 MB L3 and passes hit HBM).
// ---------------------------------------------------------------------------
__global__ void p1_read(const float4* __restrict__ hist4,
                        const float4* __restrict__ probe4,
                        float* __restrict__ sink) {
    const long long stride = (long long)gridDim.x * blockDim.x;
    const long long t0 = (long long)blockIdx.x * blockDim.x + threadIdx.x;
    float acc = 0.f;
    for (int p = 0; p < 6; ++p) {
        const float4* __restrict__ src = (p & 1) ? probe4 : hist4;
        for (long long g = t0; g < NG4; g += stride) {
            float4 v = src[g];
            acc += v.x + v.y + v.z + v.w;
        }
    }
    sink[t0] = acc; // keep live; sink is scratch
}

// ---------------------------------------------------------------------------
// p2: pure-WRITE probe hitting the REAL dst region (16B-off-128B stream),
// alternating with a ws region (L3 thrash). 6 passes.
// ---------------------------------------------------------------------------
__global__ void p2_write_real(float* __restrict__ outh,
                              float4* __restrict__ ws4) {
    const long long stride = (long long)gridDim.x * blockDim.x;
    const long long t0 = (long long)blockIdx.x * blockDim.x + threadIdx.x;
    const float4 z = make_float4(0.f, 0.f, 0.f, 0.f);
    for (int p = 0; p < 6; ++p) {
        if ((p & 1) == 0) {
            for (long long g = t0; g < NG; g += stride)
                *reinterpret_cast<float4*>(outh + 3 + 4 * g) = z;
        } else {
            for (long long g = t0; g < NG4; g += stride)
                ws4[g] = z;
        }
    }
}

// ---------------------------------------------------------------------------
// p3: pure-WRITE probe, all-ws baseline (both regions 128B-aligned). 6 passes.
// ---------------------------------------------------------------------------
__global__ void p3_write_ws(float4* __restrict__ a,
                            float4* __restrict__ b) {
    const long long stride = (long long)gridDim.x * blockDim.x;
    const long long t0 = (long long)blockIdx.x * blockDim.x + threadIdx.x;
    const float4 z = make_float4(0.f, 0.f, 0.f, 0.f);
    for (int p = 0; p < 6; ++p) {
        float4* __restrict__ dst = (p & 1) ? b : a;
        for (long long g = t0; g < NG4; g += stride)
            dst[g] = z;
    }
}

// ---------------------------------------------------------------------------
// p4: aligned COPY probe hist -> ws (the m13 pattern: float4 both sides,
// both 128B-aligned streams). 3 passes = same total traffic as p1/p2/p3.
// ---------------------------------------------------------------------------
__global__ void p4_copy_ws(const float4* __restrict__ hist4,
                           float4* __restrict__ dst) {
    const long long stride = (long long)gridDim.x * blockDim.x;
    const long long t0 = (long long)blockIdx.x * blockDim.x + threadIdx.x;
    for (int p = 0; p < 3; ++p)
        for (long long g = t0; g < NG4; g += stride)
            dst[g] = hist4[g];
}

// ---------------------------------------------------------------------------
// p5: the REAL copy (R3's verified shuffle-realign structure), 3 passes.
// Runs last among probes -> leaves the correct final history copy.
// ---------------------------------------------------------------------------
template <int KU>
__global__ void p5_copy_real(const float* __restrict__ hist,
                             float* __restrict__ out) {
    float* __restrict__ outh = out + ACT_ELEMS + 1;
    const float4* __restrict__ src = reinterpret_cast<const float4*>(hist);
    const int lane = threadIdx.x & 63;
    const long long chunk = (long long)blockDim.x * KU;

    for (int p = 0; p < 3; ++p) {
        for (long long c = blockIdx.x; c * chunk < NG; c += gridDim.x) {
            const long long g0 = c * chunk + threadIdx.x;
            float4 v[KU];
            #pragma unroll
            for (int k = 0; k < KU; ++k) {
                const long long g = g0 + (long long)k * blockDim.x;
                if (g <= NG) v[k] = src[g];
            }
            #pragma unroll
            for (int k = 0; k < KU; ++k) {
                const long long g = g0 + (long long)k * blockDim.x;
                float nx = __shfl_down(v[k].x, 1);
                float ny = __shfl_down(v[k].y, 1);
                float nz = __shfl_down(v[k].z, 1);
                if (g < NG) {
                    if (lane == 63) {
                        nx = hist[4 * (g + 1) + 0];
                        ny = hist[4 * (g + 1) + 1];
                        nz = hist[4 * (g + 1) + 2];
                    }
                    *reinterpret_cast<float4*>(outh + 3 + 4 * g) =
                        make_float4(v[k].w, nx, ny, nz);
                }
            }
        }
    }
    if (blockIdx.x == 0 && threadIdx.x == 0) {
        outh[0] = hist[0];
        outh[1] = hist[1];
        outh[2] = hist[2];
        outh[HIST_ELEMS - 1] = hist[HIST_ELEMS - 1];
    }
}

// ---------------------------------------------------------------------------
// update: one wave per sample; fused activations passthrough; atomic scatter.
// ---------------------------------------------------------------------------
__global__ void update_kernel(const float* __restrict__ act,
                              const float* __restrict__ hist,
                              const int* __restrict__ samples,
                              float* __restrict__ out,
                              float* __restrict__ partial) {
    const int s    = blockIdx.x;
    const int lane = threadIdx.x;

    const float4* __restrict__ arow = reinterpret_cast<const float4*>(act + (long long)s * D);
    float4* __restrict__ aout = reinterpret_cast<float4*>(out + (long long)s * D);
    const float4 a0 = arow[lane];
    const float4 a1 = arow[lane + 64];
    aout[lane]      = a0;
    aout[lane + 64] = a1;

    const int id = samples[s];
    const bool active = (id > 0) && (id < MAX_ITEMS);

    float sumsq = 0.0f;
    if (active) {
        const float4* __restrict__ orow =
            reinterpret_cast<const float4*>(hist + (long long)id * D);
        float* __restrict__ newh = out + ACT_ELEMS + 1 + (long long)id * D;
        const float4 o0 = orow[lane];
        const float4 o1 = orow[lane + 64];
        {
            const float dx = a0.x - o0.x, dy = a0.y - o0.y;
            const float dz = a0.z - o0.z, dw = a0.w - o0.w;
            sumsq += dx * dx + dy * dy + dz * dz + dw * dw;
            const int e = lane * 4;
            atomicAdd(newh + e + 0, 0.1f * dx);
            atomicAdd(newh + e + 1, 0.1f * dy);
            atomicAdd(newh + e + 2, 0.1f * dz);
            atomicAdd(newh + e + 3, 0.1f * dw);
        }
        {
            const float dx = a1.x - o1.x, dy = a1.y - o1.y;
            const float dz = a1.z - o1.z, dw = a1.w - o1.w;
            sumsq += dx * dx + dy * dy + dz * dz + dw * dw;
            const int e = (lane + 64) * 4;
            atomicAdd(newh + e + 0, 0.1f * dx);
            atomicAdd(newh + e + 1, 0.1f * dy);
            atomicAdd(newh + e + 2, 0.1f * dz);
            atomicAdd(newh + e + 3, 0.1f * dw);
        }
    }
    #pragma unroll
    for (int off = 32; off; off >>= 1)
        sumsq += __shfl_down(sumsq, off);
    if (lane == 0) partial[s] = sumsq;
}

__global__ void loss_kernel(const float* __restrict__ partial,
                            const int* __restrict__ iters,
                            float* __restrict__ out) {
    __shared__ float sm[256];
    const int t = threadIdx.x;
    float s = 0.0f;
    for (int i = t; i < B; i += 256) s += partial[i];
    sm[t] = s;
    __syncthreads();
    #pragma unroll
    for (int w = 128; w; w >>= 1) {
        if (t < w) sm[t] += sm[t + w];
        __syncthreads();
    }
    if (t == 0) {
        const float it = (float)iters[0];
        const float wr = (float)(1.0 / 1000.0)   * it;
        const float cr = (float)(1.0 / 100000.0) * it;
        const float weight = 0.1f * wr / (1.0f + wr) / (1.0f + cr);
        out[ACT_ELEMS] = (sm[0] / (float)D / (float)B) * weight;
    }
}

extern "C" void kernel_launch(void* const* d_in, const int* in_sizes, int n_in,
                              void* d_out, int out_size, void* d_ws, size_t ws_size,
                              hipStream_t stream) {
    const float* act     = (const float*)d_in[0];
    const float* hist    = (const float*)d_in[1];
    const int*   samples = (const int*)d_in[2];
    const int*   iters   = (const int*)d_in[3];
    float* out     = (float*)d_out;
    float* wsf     = (float*)d_ws;
    float* partial = wsf; // 16 KiB

    // probe regions in ws: two 205 MB buffers at +16 MB and +16MB+205MB
    float* probeA = wsf + (4ll << 20);
    float* probeB = probeA + NG4 * 4;
    const size_t need_bytes = ((4ll << 20) + 8ll * NG4) * 4ll;
    const bool big_ws = ws_size >= need_bytes;

    if (big_ws) {
        p1_read<<<2048, 256, 0, stream>>>(
            (const float4*)hist, (const float4*)probeA, probeB);
        p2_write_real<<<2048, 256, 0, stream>>>(
            out + ACT_ELEMS + 1, (float4*)probeB);
        p3_write_ws<<<2048, 256, 0, stream>>>(
            (float4*)probeA, (float4*)probeB);
        p4_copy_ws<<<2048, 256, 0, stream>>>(
            (const float4*)hist, (float4*)probeA);
    }
    p5_copy_real<8><<<2048, 256, 0, stream>>>(hist, out);
    update_kernel<<<B, 64, 0, stream>>>(act, hist, samples, out, partial);
    loss_kernel<<<1, 256, 0, stream>>>(partial, iters, out);
}

// Round 6
// 108.694 us; speedup vs baseline: 9.4753x; 9.4753x over previous
//
#include <hip/hip_runtime.h>

#define MAX_ITEMS 100000
constexpr int B = 4096;
constexpr int D = 512;
constexpr long long ACT_ELEMS  = (long long)B * D;               // 2097152
constexpr long long HIST_ELEMS = (long long)(MAX_ITEMS + 1) * D; // 51200512
constexpr long long NG = (HIST_ELEMS - 3) / 4; // 12800127 dst-aligned float4 groups
// d_out layout: [0, ACT) activations, [ACT] loss, [ACT+1, ACT+1+HIST) new_history.
// outh = out + ACT+1 (4B-aligned); outh+3 IS 16B-aligned.

// native clang vector type: __builtin_nontemporal_store accepts this,
// but NOT HIP_vector_type<float,4> (a struct).
typedef float f32x4 __attribute__((ext_vector_type(4)));

// ---------------------------------------------------------------------------
// Kernel 1: history -> out[ACT+1..). dwordx4 both sides; dst group g =
// {src[g].w, src[g+1].xyz} realigned in-register via __shfl_down; lane 63
// patches with 3 scalar loads. ALL bulk stores are NON-TEMPORAL so the write
// stream does not evict hist from L3 (reads are the slow direction; keeping
// hist L3-resident across replays is the win).
// ---------------------------------------------------------------------------
template <int KU>
__global__ void copy_hist_kernel(const float* __restrict__ hist,
                                 float* __restrict__ out) {
    float* __restrict__ outh = out + ACT_ELEMS + 1;
    const float4* __restrict__ src = reinterpret_cast<const float4*>(hist);
    const int lane = threadIdx.x & 63;
    const long long chunk = (long long)blockDim.x * KU;

    for (long long c = blockIdx.x; c * chunk < NG; c += gridDim.x) {
        const long long g0 = c * chunk + threadIdx.x;
        float4 v[KU];
        #pragma unroll
        for (int k = 0; k < KU; ++k) {
            const long long g = g0 + (long long)k * blockDim.x;
            if (g <= NG) v[k] = src[g];   // group NG is valid src memory
        }
        #pragma unroll
        for (int k = 0; k < KU; ++k) {
            const long long g = g0 + (long long)k * blockDim.x;
            const float nx = __shfl_down(v[k].x, 1);
            const float ny = __shfl_down(v[k].y, 1);
            const float nz = __shfl_down(v[k].z, 1);
            if (g < NG) {
                f32x4 w;
                w.x = v[k].w; w.y = nx; w.z = ny; w.w = nz;
                if (lane == 63) { // g+1 lives in the next wave: patch scalar
                    w.y = hist[4 * (g + 1) + 0];
                    w.z = hist[4 * (g + 1) + 1];
                    w.w = hist[4 * (g + 1) + 2];
                }
                __builtin_nontemporal_store(
                    w, reinterpret_cast<f32x4*>(outh + 3 + 4 * g));
            }
        }
    }
    if (blockIdx.x == 0 && threadIdx.x == 0) {
        __builtin_nontemporal_store(hist[0], outh + 0);
        __builtin_nontemporal_store(hist[1], outh + 1);
        __builtin_nontemporal_store(hist[2], outh + 2);
        __builtin_nontemporal_store(hist[HIST_ELEMS - 1], outh + HIST_ELEMS - 1);
    }
}

// ---------------------------------------------------------------------------
// Kernel 2: one wave per sample. NT-stores the act passthrough (nobody reads
// it back), gathers old row from ORIGINAL history (L3-resident), wave-reduces
// squared diff -> partial[s], atomicAdd-scatters the EMA update (duplicates
// must accumulate). Runs after copy_hist in stream order.
// ---------------------------------------------------------------------------
__global__ void update_kernel(const float* __restrict__ act,
                              const float* __restrict__ hist,
                              const int* __restrict__ samples,
                              float* __restrict__ out,
                              float* __restrict__ partial) {
    const int s    = blockIdx.x;
    const int lane = threadIdx.x; // 0..63

    const f32x4* __restrict__ arow =
        reinterpret_cast<const f32x4*>(act + (long long)s * D);
    f32x4* __restrict__ aout = reinterpret_cast<f32x4*>(out + (long long)s * D);
    const f32x4 a0 = arow[lane];
    const f32x4 a1 = arow[lane + 64];
    __builtin_nontemporal_store(a0, aout + lane);
    __builtin_nontemporal_store(a1, aout + lane + 64);

    const int id = samples[s];
    const bool active = (id > 0) && (id < MAX_ITEMS);

    float sumsq = 0.0f;
    if (active) {
        const f32x4* __restrict__ orow =
            reinterpret_cast<const f32x4*>(hist + (long long)id * D);
        float* __restrict__ newh = out + ACT_ELEMS + 1 + (long long)id * D;
        const f32x4 o0 = orow[lane];
        const f32x4 o1 = orow[lane + 64];
        {
            const float dx = a0.x - o0.x, dy = a0.y - o0.y;
            const float dz = a0.z - o0.z, dw = a0.w - o0.w;
            sumsq += dx * dx + dy * dy + dz * dz + dw * dw;
            const int e = lane * 4;
            atomicAdd(newh + e + 0, 0.1f * dx);
            atomicAdd(newh + e + 1, 0.1f * dy);
            atomicAdd(newh + e + 2, 0.1f * dz);
            atomicAdd(newh + e + 3, 0.1f * dw);
        }
        {
            const float dx = a1.x - o1.x, dy = a1.y - o1.y;
            const float dz = a1.z - o1.z, dw = a1.w - o1.w;
            sumsq += dx * dx + dy * dy + dz * dz + dw * dw;
            const int e = (lane + 64) * 4;
            atomicAdd(newh + e + 0, 0.1f * dx);
            atomicAdd(newh + e + 1, 0.1f * dy);
            atomicAdd(newh + e + 2, 0.1f * dz);
            atomicAdd(newh + e + 3, 0.1f * dw);
        }
    }
    #pragma unroll
    for (int off = 32; off; off >>= 1)
        sumsq += __shfl_down(sumsq, off);
    if (lane == 0) partial[s] = sumsq; // masked rows contribute exactly 0
}

// ---------------------------------------------------------------------------
// Kernel 3: deterministic single-block reduction of 4096 partials -> loss.
// ---------------------------------------------------------------------------
__global__ void loss_kernel(const float* __restrict__ partial,
                            const int* __restrict__ iters,
                            float* __restrict__ out) {
    __shared__ float sm[256];
    const int t = threadIdx.x;
    float s = 0.0f;
    for (int i = t; i < B; i += 256) s += partial[i];
    sm[t] = s;
    __syncthreads();
    #pragma unroll
    for (int w = 128; w; w >>= 1) {
        if (t < w) sm[t] += sm[t + w];
        __syncthreads();
    }
    if (t == 0) {
        const float it = (float)iters[0];
        const float wr = (float)(1.0 / 1000.0)   * it;
        const float cr = (float)(1.0 / 100000.0) * it;
        const float weight = 0.1f * wr / (1.0f + wr) / (1.0f + cr);
        out[ACT_ELEMS] = (sm[0] / (float)D / (float)B) * weight;
    }
}

extern "C" void kernel_launch(void* const* d_in, const int* in_sizes, int n_in,
                              void* d_out, int out_size, void* d_ws, size_t ws_size,
                              hipStream_t stream) {
    const float* act     = (const float*)d_in[0];
    const float* hist    = (const float*)d_in[1];
    const int*   samples = (const int*)d_in[2];
    const int*   iters   = (const int*)d_in[3];
    float* out     = (float*)d_out;
    float* partial = (float*)d_ws; // B*4 = 16 KiB scratch

    copy_hist_kernel<8><<<2048, 256, 0, stream>>>(hist, out);
    update_kernel<<<B, 64, 0, stream>>>(act, hist, samples, out, partial);
    loss_kernel<<<1, 256, 0, stream>>>(partial, iters, out);
}